// Round 13
// baseline (232.725 us; speedup 1.0000x reference)
//
#include <hip/hip_runtime.h>

// ---------------------------------------------------------------------------
// MDNV2 fused kernels for MI355X (gfx950) — round 13
//
// vs R12 (204 us): pair_kernel made BARRIER-FREE and LDS-FREE.
//  * B-fragments read directly from L2 (W2q panel, 36 KB, read-only,
//    L1/L2-resident) as coalesced 1KB i64x2 wave-loads; no staging, no
//    __syncthreads -> waves fully independent, stores continuously fed.
//  * #pragma unroll 1 on sp-loop bounds in-flight load VGPRs.
//  * softmax max-pass dropped (logits provably << f32-exp overflow bound).
//  * prep + dist merged into one setup kernel (one fewer launch).
// fp8 e4m3 GEMM2 (weights x16), bf16 Lq/Pq as before.
// ---------------------------------------------------------------------------

typedef __attribute__((ext_vector_type(4))) float f32x4;
typedef __attribute__((ext_vector_type(4))) unsigned int u32x4;
typedef __attribute__((ext_vector_type(8))) short bf16x8;
typedef __attribute__((ext_vector_type(2))) long i64x2;

#define M_TOT 327680
#define WSCALE 16.0f
#define WDESCALE 0.0625f

__device__ __forceinline__ unsigned short f2bf(float f) {
    union { float f; unsigned int u; } v; v.f = f;
    unsigned int r = (v.u + 0x7FFFu + ((v.u >> 16) & 1u)) >> 16;  // RNE
    return (unsigned short)r;
}

__device__ __forceinline__ float eluf(float y) {
    return fmaxf(y, 0.f) + __expf(fminf(y, 0.f)) - 1.f;
}

__device__ __forceinline__ float bfhalf_lo(unsigned int u) {
    return __uint_as_float(u << 16);
}
__device__ __forceinline__ float bfhalf_hi(unsigned int u) {
    return __uint_as_float(u & 0xFFFF0000u);
}

__device__ __forceinline__ void pair_decode(int m0, int& b, int& cl, int& cp0) {
    unsigned int P = (unsigned int)m0 / 40960u;
    unsigned int r = (unsigned int)m0 % 40960u;
    if (r < 8192u) {            // even batch: 32 lig x 256 prot
        b = 2 * (int)P; cl = 96 * (int)P + (int)(r >> 8); cp0 = 768 * (int)P + (int)(r & 255u);
    } else {                    // odd batch: 64 lig x 512 prot
        unsigned int rr = r - 8192u;
        b = 2 * (int)P + 1; cl = 96 * (int)P + 32 + (int)(rr >> 9);
        cp0 = 768 * (int)P + 256 + (int)(rr & 511u);
    }
}

// ---------------------------------------------------------------------------
// setup_kernel: blocks 0..431 = weight prep + folded tails; blocks 432..1711
// = dist + pair_b (256 pair-rows each). ws layout (bytes):
//   W1T @0      : [256 n][256 k] bf16                                131072
//   W2q @131072 : fp8 [head 3][f 9][sp 4][lane 64][h 2][j 8]         110592
//   b2s @241664 : [3][144] f32 (bias x16, pads zero)                   1728
//   a1  @243392 : [256] f32
//   cs  @244416 : [256] f32
//   Lq  @245440 : [768][256] bf16
//   Pq  @638656 : [6144][256] bf16  (3 MB -> L2-resident)
// ---------------------------------------------------------------------------
__global__ void setup_kernel(const float* __restrict__ W1, const float* __restrict__ b1,
                             const float* __restrict__ gamma, const float* __restrict__ beta,
                             const float* __restrict__ rmean, const float* __restrict__ rvar,
                             const float* __restrict__ Wpi, const float* __restrict__ bpi,
                             const float* __restrict__ Wsig, const float* __restrict__ bsig,
                             const float* __restrict__ Wmu, const float* __restrict__ bmu,
                             const float* __restrict__ h_l,
                             const int* __restrict__ esrc, const int* __restrict__ edst,
                             const float* __restrict__ Wat, const float* __restrict__ bat,
                             const float* __restrict__ Wbt, const float* __restrict__ bbt,
                             const float* __restrict__ lig_pos, const float* __restrict__ prot_pos,
                             unsigned short* __restrict__ W1T, unsigned char* __restrict__ W2q,
                             float* __restrict__ b2s, float* __restrict__ a1v, float* __restrict__ csv,
                             float* __restrict__ out_at, float* __restrict__ out_bt,
                             float* __restrict__ out_dist, float* __restrict__ out_pb) {
    if (blockIdx.x >= 432) {
        // ---- dist + pair_b: 256 pair-rows per block ----
        const int m0 = (blockIdx.x - 432) * 256;
        int b, cl, cp0;
        pair_decode(m0, b, cl, cp0);
        const int rw = threadIdx.x;
        float lx = lig_pos[cl * 3 + 0];
        float ly = lig_pos[cl * 3 + 1];
        float lz = lig_pos[cl * 3 + 2];
        const float* pp = prot_pos + (size_t)(cp0 + rw) * 42;
        float* dr = out_dist + (size_t)(m0 + rw) * 14;
        #pragma unroll
        for (int a = 0; a < 14; ++a) {
            float dx = lx - pp[a * 3 + 0];
            float dy = ly - pp[a * 3 + 1];
            float dz = lz - pp[a * 3 + 2];
            dr[a] = sqrtf(dx * dx + dy * dy + dz * dz);
        }
        out_pb[m0 + rw] = (float)b;
        return;
    }

    int idx = blockIdx.x * 256 + threadIdx.x;          // 432 blocks -> 110592
    {
        int j    = idx & 7;
        int h    = (idx >> 3) & 1;
        int lane = (idx >> 4) & 63;
        int sp   = (idx >> 10) & 3;
        int t    = idx >> 12;                          // 0..26
        int f    = t % 9;
        int head = t / 9;
        int k    = (sp * 2 + h) * 32 + (lane >> 4) * 8 + j;
        int col  = f * 16 + (lane & 15);
        float v = 0.f;
        if (col < 140) {
            const float* Wh = (head == 0) ? Wpi : (head == 1) ? Wsig : Wmu;
            v = Wh[k * 140 + col] * WSCALE;
        }
        W2q[idx] = (unsigned char)(__builtin_amdgcn_cvt_pk_fp8_f32(v, 0.f, 0, false) & 0xFF);
    }
    if (idx < 256 * 256) {                             // W1T[n][k] = W1[k][n], coalesced reads
        int n = idx & 255, k = idx >> 8;
        W1T[n * 256 + k] = f2bf(W1[k * 256 + n]);
    }
    if (idx < 432) {                                   // b2s[head][col]
        int head = idx / 144, col = idx % 144;
        float v = 0.f;
        if (col < 140) v = (head == 0) ? bpi[col] : (head == 1) ? bsig[col] : bmu[col];
        b2s[idx] = v * WSCALE;
    }
    if (idx < 256) {
        float s = gamma[idx] * rsqrtf(rvar[idx] + 1e-5f);
        a1v[idx] = s;
        csv[idx] = s * (b1[idx] - rmean[idx]) + beta[idx];
    }
    // ---- folded tail: atom_types [768,17], bond_types [2048,5] ----
    if (idx < 768 * 17) {
        int row = idx / 17, c = idx % 17;
        const float* hr = h_l + (size_t)row * 128;
        float s = bat[c];
        #pragma unroll 4
        for (int k = 0; k < 128; ++k) s += hr[k] * Wat[k * 17 + c];
        out_at[idx] = s;
    } else if (idx < 768 * 17 + 2048 * 5) {
        int t2 = idx - 768 * 17;
        int e = t2 / 5, c = t2 % 5;
        const float* hs = h_l + (size_t)esrc[e] * 128;
        const float* hd = h_l + (size_t)edst[e] * 128;
        float s = bbt[c];
        #pragma unroll 4
        for (int k = 0; k < 128; ++k)
            s += hs[k] * Wbt[k * 5 + c] + hd[k] * Wbt[(k + 128) * 5 + c];
        out_bt[t2] = s;
    }
}

// ---------------------------------------------------------------------------
// node_gemm: Lq (BN shift folded) / Pq (scale only), bf16 output.
// grid 216 = 108 row-blocks x 2 N-halves (8 fragments each).
// ---------------------------------------------------------------------------
__global__ __launch_bounds__(256, 2) void node_gemm(
        const float* __restrict__ h_l, const float* __restrict__ h_p,
        const unsigned short* __restrict__ W1T,
        const float* __restrict__ a1v, const float* __restrict__ csv,
        unsigned short* __restrict__ Lq, unsigned short* __restrict__ Pq) {
    const int tid = threadIdx.x, lane = tid & 63, w = tid >> 6;
    const int cGrp = lane & 15, g = lane >> 4;
    const int nh   = blockIdx.x & 1;
    const int row0 = (blockIdx.x >> 1) * 64;
    const bool isLig = row0 < 768;
    const float* src = isLig ? (h_l + (size_t)row0 * 128) : (h_p + (size_t)(row0 - 768) * 128);
    unsigned short* dst = isLig ? (Lq + (size_t)row0 * 256) : (Pq + (size_t)(row0 - 768) * 256);
    const int koff = isLig ? 0 : 128;

    f32x4 acc[8];
    #pragma unroll
    for (int fn = 0; fn < 8; ++fn) acc[fn] = (f32x4){0.f, 0.f, 0.f, 0.f};

    #pragma unroll
    for (int fk = 0; fk < 4; ++fk) {
        const float* ap = src + (size_t)(w * 16 + cGrp) * 128 + fk * 32 + g * 8;
        f32x4 qa = *(const f32x4*)ap;
        f32x4 qb = *(const f32x4*)(ap + 4);
        bf16x8 af;
        af[0] = (short)f2bf(qa[0]); af[1] = (short)f2bf(qa[1]);
        af[2] = (short)f2bf(qa[2]); af[3] = (short)f2bf(qa[3]);
        af[4] = (short)f2bf(qb[0]); af[5] = (short)f2bf(qb[1]);
        af[6] = (short)f2bf(qb[2]); af[7] = (short)f2bf(qb[3]);
        #pragma unroll
        for (int fn = 0; fn < 8; ++fn) {
            int n = nh * 128 + fn * 16 + cGrp;
            bf16x8 bf = *(const bf16x8*)(W1T + (size_t)n * 256 + koff + fk * 32 + g * 8);
            acc[fn] = __builtin_amdgcn_mfma_f32_16x16x32_bf16(af, bf, acc[fn], 0, 0, 0);
        }
    }
    #pragma unroll
    for (int fn = 0; fn < 8; ++fn) {
        int h = nh * 128 + fn * 16 + cGrp;
        float s = a1v[h];
        float c0 = isLig ? csv[h] : 0.f;
        #pragma unroll
        for (int rg = 0; rg < 4; ++rg)
            dst[(size_t)(w * 16 + g * 4 + rg) * 256 + h] = f2bf(s * acc[fn][rg] + c0);
    }
}

// ---------------------------------------------------------------------------
// pair_kernel: grid (5120, 3 heads), block 256 (4 waves).
// BARRIER-FREE, LDS-FREE: B-fragments read directly from L2 (coalesced
// 1KB i64x2 wave-loads of the 36KB read-only panel). Waves fully
// independent -> loads/VALU/MFMA/stores of different waves drift freely.
// ---------------------------------------------------------------------------
__global__ __launch_bounds__(256, 6) void pair_kernel(
        const unsigned short* __restrict__ Lq, const unsigned short* __restrict__ Pq,
        const unsigned char* __restrict__ W2q, const float* __restrict__ b2s,
        float* __restrict__ out_pi, float* __restrict__ out_sig, float* __restrict__ out_mu) {

    const int tid = threadIdx.x, lane = tid & 63, w = tid >> 6;
    const int c = lane & 15, g = lane >> 4;
    const int head = blockIdx.y;
    const int m0 = blockIdx.x * 64;

    int b, cl, cp0;
    pair_decode(m0, b, cl, cp0);

    // ---- bias (x16 prescaled) ----
    float bb[9];
    #pragma unroll
    for (int f = 0; f < 9; ++f) bb[f] = b2s[head * 144 + f * 16 + c];

    // ---- X = fp8(elu(Lq+Pq)) in registers (A-fragment layout) ----
    const int row = w * 16 + c;
    const unsigned short* pqp = Pq + (size_t)(cp0 + row) * 256;
    const unsigned short* lqp = Lq + (size_t)cl * 256;
    long Xa[8];
    #pragma unroll
    for (int s = 0; s < 8; ++s) {
        u32x4 pv = *(const u32x4*)(pqp + s * 32 + g * 8);
        u32x4 lv = *(const u32x4*)(lqp + s * 32 + g * 8);
        float y0 = eluf(bfhalf_lo(pv[0]) + bfhalf_lo(lv[0]));
        float y1 = eluf(bfhalf_hi(pv[0]) + bfhalf_hi(lv[0]));
        float y2 = eluf(bfhalf_lo(pv[1]) + bfhalf_lo(lv[1]));
        float y3 = eluf(bfhalf_hi(pv[1]) + bfhalf_hi(lv[1]));
        float y4 = eluf(bfhalf_lo(pv[2]) + bfhalf_lo(lv[2]));
        float y5 = eluf(bfhalf_hi(pv[2]) + bfhalf_hi(lv[2]));
        float y6 = eluf(bfhalf_lo(pv[3]) + bfhalf_lo(lv[3]));
        float y7 = eluf(bfhalf_hi(pv[3]) + bfhalf_hi(lv[3]));
        unsigned int lo = (unsigned int)__builtin_amdgcn_cvt_pk_fp8_f32(y0, y1, 0, false);
        lo = (unsigned int)__builtin_amdgcn_cvt_pk_fp8_f32(y2, y3, (int)lo, true);
        unsigned int hi = (unsigned int)__builtin_amdgcn_cvt_pk_fp8_f32(y4, y5, 0, false);
        hi = (unsigned int)__builtin_amdgcn_cvt_pk_fp8_f32(y6, y7, (int)hi, true);
        Xa[s] = (long)(((unsigned long long)hi << 32) | (unsigned long long)lo);
    }

    // ---- K-loop: B-fragments straight from L2 (no LDS, no barrier) ----
    f32x4 acc[9];
    #pragma unroll
    for (int f = 0; f < 9; ++f) acc[f] = (f32x4){bb[f], bb[f], bb[f], bb[f]};

    const unsigned char* wp0 = W2q + (size_t)head * 36864 + lane * 16;
    #pragma unroll 1
    for (int sp = 0; sp < 4; ++sp) {
        long xa0 = Xa[2 * sp], xa1 = Xa[2 * sp + 1];
        const unsigned char* wp = wp0 + sp * 1024;
        #pragma unroll
        for (int f = 0; f < 9; ++f) {
            i64x2 bq = *(const i64x2*)(wp + f * 4096);
            acc[f] = __builtin_amdgcn_mfma_f32_16x16x32_fp8_fp8(xa0, bq[0], acc[f], 0, 0, 0);
            acc[f] = __builtin_amdgcn_mfma_f32_16x16x32_fp8_fp8(xa1, bq[1], acc[f], 0, 0, 0);
        }
    }

    // ---- de-scale ----
    #pragma unroll
    for (int f = 0; f < 9; ++f)
        #pragma unroll
        for (int q = 0; q < 4; ++q) acc[f][q] *= WDESCALE;

    const bool v8 = (c < 12);   // frag 8 covers cols 128..143, valid < 140

    if (head == 0) {
        // ---- pi softmax, NO max-subtraction: |logit| <= 256*max|x|*max|w|
        // (x fp8 <= ~8, w/16 <= ~0.1) << 88 = f32 exp overflow bound. ----
        #pragma unroll
        for (int q = 0; q < 4; ++q) {
            float e0 = __expf(acc[0][q]), e1 = __expf(acc[1][q]);
            float e2 = __expf(acc[2][q]), e3 = __expf(acc[3][q]);
            float e4 = __expf(acc[4][q]), e5 = __expf(acc[5][q]);
            float e6 = __expf(acc[6][q]), e7 = __expf(acc[7][q]);
            float e8 = v8 ? __expf(acc[8][q]) : 0.f;
            float sm = ((e0 + e1) + (e2 + e3)) + ((e4 + e5) + (e6 + e7)) + e8;
            sm += __shfl_xor(sm, 1, 64);
            sm += __shfl_xor(sm, 2, 64);
            sm += __shfl_xor(sm, 4, 64);
            sm += __shfl_xor(sm, 8, 64);
            float inv = 1.f / sm;
            const int gr = m0 + w * 16 + g * 4 + q;
            float* prow = out_pi + (size_t)gr * 140;
            prow[c]       = e0 * inv;  prow[16 + c]  = e1 * inv;
            prow[32 + c]  = e2 * inv;  prow[48 + c]  = e3 * inv;
            prow[64 + c]  = e4 * inv;  prow[80 + c]  = e5 * inv;
            prow[96 + c]  = e6 * inv;  prow[112 + c] = e7 * inv;
            if (v8) prow[128 + c] = e8 * inv;
        }
    } else {
        const float addc = (head == 1) ? 1.1f : 1.0f;
        float* outh = (head == 1) ? out_sig : out_mu;
        #pragma unroll
        for (int q = 0; q < 4; ++q) {
            const int gr = m0 + w * 16 + g * 4 + q;
            float* rowp = outh + (size_t)gr * 140;
            rowp[c]       = eluf(acc[0][q]) + addc;
            rowp[16 + c]  = eluf(acc[1][q]) + addc;
            rowp[32 + c]  = eluf(acc[2][q]) + addc;
            rowp[48 + c]  = eluf(acc[3][q]) + addc;
            rowp[64 + c]  = eluf(acc[4][q]) + addc;
            rowp[80 + c]  = eluf(acc[5][q]) + addc;
            rowp[96 + c]  = eluf(acc[6][q]) + addc;
            rowp[112 + c] = eluf(acc[7][q]) + addc;
            if (v8) rowp[128 + c] = eluf(acc[8][q]) + addc;
        }
    }
}

// ---------------------------------------------------------------------------
extern "C" void kernel_launch(void* const* d_in, const int* in_sizes, int n_in,
                              void* d_out, int out_size, void* d_ws, size_t ws_size,
                              hipStream_t stream) {
    const float* h_l      = (const float*)d_in[0];
    const float* h_p      = (const float*)d_in[1];
    const float* lig_pos  = (const float*)d_in[2];
    const float* prot_pos = (const float*)d_in[3];
    const int*   esrc     = (const int*)d_in[4];
    const int*   edst     = (const int*)d_in[5];
    const float* W1    = (const float*)d_in[12];
    const float* b1    = (const float*)d_in[13];
    const float* gamma = (const float*)d_in[14];
    const float* beta  = (const float*)d_in[15];
    const float* rmean = (const float*)d_in[16];
    const float* rvar  = (const float*)d_in[17];
    const float* Wpi   = (const float*)d_in[18];
    const float* bpi   = (const float*)d_in[19];
    const float* Wsig  = (const float*)d_in[20];
    const float* bsig  = (const float*)d_in[21];
    const float* Wmu   = (const float*)d_in[22];
    const float* bmu   = (const float*)d_in[23];
    const float* Wat   = (const float*)d_in[24];
    const float* bat   = (const float*)d_in[25];
    const float* Wbt   = (const float*)d_in[26];
    const float* bbt   = (const float*)d_in[27];

    char* ws = (char*)d_ws;
    unsigned short* W1T = (unsigned short*)(ws + 0);
    unsigned char*  W2q = (unsigned char*)(ws + 131072);
    float*          b2s = (float*)(ws + 241664);
    float*          a1v = (float*)(ws + 243392);
    float*          csv = (float*)(ws + 244416);
    unsigned short* Lq  = (unsigned short*)(ws + 245440);
    unsigned short* Pq  = (unsigned short*)(ws + 638656);

    float* out = (float*)d_out;
    const size_t M = M_TOT;
    float* out_pi   = out;
    float* out_sig  = out + M * 140;
    float* out_mu   = out + 2 * M * 140;
    float* out_dist = out + 3 * M * 140;
    float* out_at   = out + 3 * M * 140 + M * 14;
    float* out_bt   = out_at + 768 * 17;
    float* out_pb   = out_bt + 2048 * 5;

    hipLaunchKernelGGL(setup_kernel, dim3(432 + M_TOT / 256), dim3(256), 0, stream,
                       W1, b1, gamma, beta, rmean, rvar,
                       Wpi, bpi, Wsig, bsig, Wmu, bmu,
                       h_l, esrc, edst, Wat, bat, Wbt, bbt,
                       lig_pos, prot_pos,
                       W1T, W2q, b2s, a1v, csv, out_at, out_bt, out_dist, out_pb);

    hipLaunchKernelGGL(node_gemm, dim3(2 * (768 + 6144) / 64), dim3(256), 0, stream,
                       h_l, h_p, W1T, a1v, csv, Lq, Pq);

    hipLaunchKernelGGL(pair_kernel, dim3(M_TOT / 64, 3), dim3(256), 0, stream,
                       Lq, Pq, W2q, b2s, out_pi, out_sig, out_mu);
}

// Round 14
// 190.849 us; speedup vs baseline: 1.2194x; 1.2194x over previous
//
#include <hip/hip_runtime.h>

// ---------------------------------------------------------------------------
// MDNV2 fused kernels for MI355X (gfx950) — round 14
//
// Base = R12 core (staged LDS panel, best 204 us). New this round:
//  * LDS-staged DENSE stores: output rows are 560 B (misaligned stride), so
//    direct per-frag column stores straddle cache lines (~2x transaction
//    amplification; measured pair write rate 3.4 TB/s = half of fill's 6.6).
//    After the K-loop the panel LDS is dead -> overlay a [64][140] f32 tile,
//    write epilogue results there, barrier, then LINEAR dwordx4 stores of the
//    contiguous 64B-aligned 35840-B tile range (full-line transactions only).
//  * 256-thr blocks (4 blocks/CU), merged setup kernel, no-max softmax.
// fp8 e4m3 GEMM2 (weights x16), bf16 Lq/Pq as before.
// ---------------------------------------------------------------------------

typedef __attribute__((ext_vector_type(4))) float f32x4;
typedef __attribute__((ext_vector_type(4))) unsigned int u32x4;
typedef __attribute__((ext_vector_type(8))) short bf16x8;

#define M_TOT 327680
#define WSCALE 16.0f
#define WDESCALE 0.0625f

__device__ __forceinline__ unsigned short f2bf(float f) {
    union { float f; unsigned int u; } v; v.f = f;
    unsigned int r = (v.u + 0x7FFFu + ((v.u >> 16) & 1u)) >> 16;  // RNE
    return (unsigned short)r;
}

__device__ __forceinline__ float eluf(float y) {
    return fmaxf(y, 0.f) + __expf(fminf(y, 0.f)) - 1.f;
}

__device__ __forceinline__ float bfhalf_lo(unsigned int u) {
    return __uint_as_float(u << 16);
}
__device__ __forceinline__ float bfhalf_hi(unsigned int u) {
    return __uint_as_float(u & 0xFFFF0000u);
}

__device__ __forceinline__ void pair_decode(int m0, int& b, int& cl, int& cp0) {
    unsigned int P = (unsigned int)m0 / 40960u;
    unsigned int r = (unsigned int)m0 % 40960u;
    if (r < 8192u) {            // even batch: 32 lig x 256 prot
        b = 2 * (int)P; cl = 96 * (int)P + (int)(r >> 8); cp0 = 768 * (int)P + (int)(r & 255u);
    } else {                    // odd batch: 64 lig x 512 prot
        unsigned int rr = r - 8192u;
        b = 2 * (int)P + 1; cl = 96 * (int)P + 32 + (int)(rr >> 9);
        cp0 = 768 * (int)P + 256 + (int)(rr & 511u);
    }
}

// ---------------------------------------------------------------------------
// setup_kernel: blocks 0..431 = weight prep + folded tails; blocks 432..1711
// = dist + pair_b (256 pair-rows each). ws layout (bytes):
//   W1T @0      : [256 n][256 k] bf16                                131072
//   W2q @131072 : fp8 [head 3][f 9][sp 4][lane 64][h 2][j 8]         110592
//   b2s @241664 : [3][144] f32 (bias x16, pads zero)                   1728
//   a1  @243392 : [256] f32
//   cs  @244416 : [256] f32
//   Lq  @245440 : [768][256] bf16
//   Pq  @638656 : [6144][256] bf16  (3 MB -> L2-resident)
// ---------------------------------------------------------------------------
__global__ void setup_kernel(const float* __restrict__ W1, const float* __restrict__ b1,
                             const float* __restrict__ gamma, const float* __restrict__ beta,
                             const float* __restrict__ rmean, const float* __restrict__ rvar,
                             const float* __restrict__ Wpi, const float* __restrict__ bpi,
                             const float* __restrict__ Wsig, const float* __restrict__ bsig,
                             const float* __restrict__ Wmu, const float* __restrict__ bmu,
                             const float* __restrict__ h_l,
                             const int* __restrict__ esrc, const int* __restrict__ edst,
                             const float* __restrict__ Wat, const float* __restrict__ bat,
                             const float* __restrict__ Wbt, const float* __restrict__ bbt,
                             const float* __restrict__ lig_pos, const float* __restrict__ prot_pos,
                             unsigned short* __restrict__ W1T, unsigned char* __restrict__ W2q,
                             float* __restrict__ b2s, float* __restrict__ a1v, float* __restrict__ csv,
                             float* __restrict__ out_at, float* __restrict__ out_bt,
                             float* __restrict__ out_dist, float* __restrict__ out_pb) {
    if (blockIdx.x >= 432) {
        // ---- dist + pair_b: 256 pair-rows per block ----
        const int m0 = (blockIdx.x - 432) * 256;
        int b, cl, cp0;
        pair_decode(m0, b, cl, cp0);
        const int rw = threadIdx.x;
        float lx = lig_pos[cl * 3 + 0];
        float ly = lig_pos[cl * 3 + 1];
        float lz = lig_pos[cl * 3 + 2];
        const float* pp = prot_pos + (size_t)(cp0 + rw) * 42;
        float* dr = out_dist + (size_t)(m0 + rw) * 14;
        #pragma unroll
        for (int a = 0; a < 14; ++a) {
            float dx = lx - pp[a * 3 + 0];
            float dy = ly - pp[a * 3 + 1];
            float dz = lz - pp[a * 3 + 2];
            dr[a] = sqrtf(dx * dx + dy * dy + dz * dz);
        }
        out_pb[m0 + rw] = (float)b;
        return;
    }

    int idx = blockIdx.x * 256 + threadIdx.x;          // 432 blocks -> 110592
    {
        int j    = idx & 7;
        int h    = (idx >> 3) & 1;
        int lane = (idx >> 4) & 63;
        int sp   = (idx >> 10) & 3;
        int t    = idx >> 12;                          // 0..26
        int f    = t % 9;
        int head = t / 9;
        int k    = (sp * 2 + h) * 32 + (lane >> 4) * 8 + j;
        int col  = f * 16 + (lane & 15);
        float v = 0.f;
        if (col < 140) {
            const float* Wh = (head == 0) ? Wpi : (head == 1) ? Wsig : Wmu;
            v = Wh[k * 140 + col] * WSCALE;
        }
        W2q[idx] = (unsigned char)(__builtin_amdgcn_cvt_pk_fp8_f32(v, 0.f, 0, false) & 0xFF);
    }
    if (idx < 256 * 256) {                             // W1T[n][k] = W1[k][n], coalesced reads
        int n = idx & 255, k = idx >> 8;
        W1T[n * 256 + k] = f2bf(W1[k * 256 + n]);
    }
    if (idx < 432) {                                   // b2s[head][col]
        int head = idx / 144, col = idx % 144;
        float v = 0.f;
        if (col < 140) v = (head == 0) ? bpi[col] : (head == 1) ? bsig[col] : bmu[col];
        b2s[idx] = v * WSCALE;
    }
    if (idx < 256) {
        float s = gamma[idx] * rsqrtf(rvar[idx] + 1e-5f);
        a1v[idx] = s;
        csv[idx] = s * (b1[idx] - rmean[idx]) + beta[idx];
    }
    // ---- folded tail: atom_types [768,17], bond_types [2048,5] ----
    if (idx < 768 * 17) {
        int row = idx / 17, c = idx % 17;
        const float* hr = h_l + (size_t)row * 128;
        float s = bat[c];
        #pragma unroll 4
        for (int k = 0; k < 128; ++k) s += hr[k] * Wat[k * 17 + c];
        out_at[idx] = s;
    } else if (idx < 768 * 17 + 2048 * 5) {
        int t2 = idx - 768 * 17;
        int e = t2 / 5, c = t2 % 5;
        const float* hs = h_l + (size_t)esrc[e] * 128;
        const float* hd = h_l + (size_t)edst[e] * 128;
        float s = bbt[c];
        #pragma unroll 4
        for (int k = 0; k < 128; ++k)
            s += hs[k] * Wbt[k * 5 + c] + hd[k] * Wbt[(k + 128) * 5 + c];
        out_bt[t2] = s;
    }
}

// ---------------------------------------------------------------------------
// node_gemm: Lq (BN shift folded) / Pq (scale only), bf16 output.
// grid 216 = 108 row-blocks x 2 N-halves (8 fragments each).
// ---------------------------------------------------------------------------
__global__ __launch_bounds__(256, 2) void node_gemm(
        const float* __restrict__ h_l, const float* __restrict__ h_p,
        const unsigned short* __restrict__ W1T,
        const float* __restrict__ a1v, const float* __restrict__ csv,
        unsigned short* __restrict__ Lq, unsigned short* __restrict__ Pq) {
    const int tid = threadIdx.x, lane = tid & 63, w = tid >> 6;
    const int cGrp = lane & 15, g = lane >> 4;
    const int nh   = blockIdx.x & 1;
    const int row0 = (blockIdx.x >> 1) * 64;
    const bool isLig = row0 < 768;
    const float* src = isLig ? (h_l + (size_t)row0 * 128) : (h_p + (size_t)(row0 - 768) * 128);
    unsigned short* dst = isLig ? (Lq + (size_t)row0 * 256) : (Pq + (size_t)(row0 - 768) * 256);
    const int koff = isLig ? 0 : 128;

    f32x4 acc[8];
    #pragma unroll
    for (int fn = 0; fn < 8; ++fn) acc[fn] = (f32x4){0.f, 0.f, 0.f, 0.f};

    #pragma unroll
    for (int fk = 0; fk < 4; ++fk) {
        const float* ap = src + (size_t)(w * 16 + cGrp) * 128 + fk * 32 + g * 8;
        f32x4 qa = *(const f32x4*)ap;
        f32x4 qb = *(const f32x4*)(ap + 4);
        bf16x8 af;
        af[0] = (short)f2bf(qa[0]); af[1] = (short)f2bf(qa[1]);
        af[2] = (short)f2bf(qa[2]); af[3] = (short)f2bf(qa[3]);
        af[4] = (short)f2bf(qb[0]); af[5] = (short)f2bf(qb[1]);
        af[6] = (short)f2bf(qb[2]); af[7] = (short)f2bf(qb[3]);
        #pragma unroll
        for (int fn = 0; fn < 8; ++fn) {
            int n = nh * 128 + fn * 16 + cGrp;
            bf16x8 bf = *(const bf16x8*)(W1T + (size_t)n * 256 + koff + fk * 32 + g * 8);
            acc[fn] = __builtin_amdgcn_mfma_f32_16x16x32_bf16(af, bf, acc[fn], 0, 0, 0);
        }
    }
    #pragma unroll
    for (int fn = 0; fn < 8; ++fn) {
        int h = nh * 128 + fn * 16 + cGrp;
        float s = a1v[h];
        float c0 = isLig ? csv[h] : 0.f;
        #pragma unroll
        for (int rg = 0; rg < 4; ++rg)
            dst[(size_t)(w * 16 + g * 4 + rg) * 256 + h] = f2bf(s * acc[fn][rg] + c0);
    }
}

// ---------------------------------------------------------------------------
// pair_kernel: grid (5120, 3 heads), block 256 (4 waves).
// Phase 1: stage 36.9 KB panel in LDS; Phase 2: X-build + K-loop + epilogue
// math in regs; Phase 3: overlay LDS with [64][140] f32 output tile; Phase 4:
// LINEAR dwordx4 stores of the contiguous 64B-aligned tile range.
// ---------------------------------------------------------------------------
__global__ __launch_bounds__(256, 4) void pair_kernel(
        const unsigned short* __restrict__ Lq, const unsigned short* __restrict__ Pq,
        const unsigned char* __restrict__ W2q, const float* __restrict__ b2s,
        float* __restrict__ out_pi, float* __restrict__ out_sig, float* __restrict__ out_mu) {

    __shared__ __align__(16) unsigned char Bs[36864];   // panel, then output tile

    const int tid = threadIdx.x, lane = tid & 63, w = tid >> 6;
    const int c = lane & 15, g = lane >> 4;
    const int head = blockIdx.y;
    const int m0 = blockIdx.x * 64;

    int b, cl, cp0;
    pair_decode(m0, b, cl, cp0);

    // ---- issue weight staging loads (9 x 16B/thread = 36864 B) ----
    const unsigned char* wsrc = W2q + (size_t)head * 36864;
    u32x4 stg[9];
    #pragma unroll
    for (int i = 0; i < 9; ++i)
        stg[i] = *(const u32x4*)(wsrc + (size_t)(tid + 256 * i) * 16);

    // ---- bias (x16 prescaled) ----
    float bb[9];
    #pragma unroll
    for (int f = 0; f < 9; ++f) bb[f] = b2s[head * 144 + f * 16 + c];

    // ---- X = fp8(elu(Lq+Pq)) in registers (A-fragment layout) ----
    const int row = w * 16 + c;
    const unsigned short* pqp = Pq + (size_t)(cp0 + row) * 256;
    const unsigned short* lqp = Lq + (size_t)cl * 256;
    long Xa[8];
    #pragma unroll
    for (int s = 0; s < 8; ++s) {
        u32x4 pv = *(const u32x4*)(pqp + s * 32 + g * 8);
        u32x4 lv = *(const u32x4*)(lqp + s * 32 + g * 8);
        float y0 = eluf(bfhalf_lo(pv[0]) + bfhalf_lo(lv[0]));
        float y1 = eluf(bfhalf_hi(pv[0]) + bfhalf_hi(lv[0]));
        float y2 = eluf(bfhalf_lo(pv[1]) + bfhalf_lo(lv[1]));
        float y3 = eluf(bfhalf_hi(pv[1]) + bfhalf_hi(lv[1]));
        float y4 = eluf(bfhalf_lo(pv[2]) + bfhalf_lo(lv[2]));
        float y5 = eluf(bfhalf_hi(pv[2]) + bfhalf_hi(lv[2]));
        float y6 = eluf(bfhalf_lo(pv[3]) + bfhalf_lo(lv[3]));
        float y7 = eluf(bfhalf_hi(pv[3]) + bfhalf_hi(lv[3]));
        unsigned int lo = (unsigned int)__builtin_amdgcn_cvt_pk_fp8_f32(y0, y1, 0, false);
        lo = (unsigned int)__builtin_amdgcn_cvt_pk_fp8_f32(y2, y3, (int)lo, true);
        unsigned int hi = (unsigned int)__builtin_amdgcn_cvt_pk_fp8_f32(y4, y5, 0, false);
        hi = (unsigned int)__builtin_amdgcn_cvt_pk_fp8_f32(y6, y7, (int)hi, true);
        Xa[s] = (long)(((unsigned long long)hi << 32) | (unsigned long long)lo);
    }

    // ---- write staged weights to LDS, barrier ----
    #pragma unroll
    for (int i = 0; i < 9; ++i)
        *(u32x4*)(Bs + (size_t)(tid + 256 * i) * 16) = stg[i];
    __syncthreads();

    // ---- K-loop: 36 conflict-free ds_read_b128 + 72 fp8 MFMA ----
    f32x4 acc[9];
    #pragma unroll
    for (int f = 0; f < 9; ++f) acc[f] = (f32x4){bb[f], bb[f], bb[f], bb[f]};

    #pragma unroll
    for (int sp = 0; sp < 4; ++sp) {
        long xa0 = Xa[2 * sp], xa1 = Xa[2 * sp + 1];
        #pragma unroll
        for (int f = 0; f < 9; ++f) {
            u32x4 bq = *(const u32x4*)(Bs + f * 4096 + sp * 1024 + lane * 16);
            long b0 = (long)(((unsigned long long)bq[1] << 32) | (unsigned long long)bq[0]);
            long b1 = (long)(((unsigned long long)bq[3] << 32) | (unsigned long long)bq[2]);
            acc[f] = __builtin_amdgcn_mfma_f32_16x16x32_fp8_fp8(xa0, b0, acc[f], 0, 0, 0);
            acc[f] = __builtin_amdgcn_mfma_f32_16x16x32_fp8_fp8(xa1, b1, acc[f], 0, 0, 0);
        }
    }

    // ---- epilogue math in regs (acc overwritten with final outputs) ----
    #pragma unroll
    for (int f = 0; f < 9; ++f)
        #pragma unroll
        for (int q = 0; q < 4; ++q) acc[f][q] *= WDESCALE;

    const bool v8 = (c < 12);   // frag 8 covers cols 128..143, valid < 140

    if (head == 0) {
        // pi softmax, no max-subtraction (|logit| << f32 exp overflow bound)
        #pragma unroll
        for (int q = 0; q < 4; ++q) {
            float e0 = __expf(acc[0][q]), e1 = __expf(acc[1][q]);
            float e2 = __expf(acc[2][q]), e3 = __expf(acc[3][q]);
            float e4 = __expf(acc[4][q]), e5 = __expf(acc[5][q]);
            float e6 = __expf(acc[6][q]), e7 = __expf(acc[7][q]);
            float e8 = v8 ? __expf(acc[8][q]) : 0.f;
            float sm = ((e0 + e1) + (e2 + e3)) + ((e4 + e5) + (e6 + e7)) + e8;
            sm += __shfl_xor(sm, 1, 64);
            sm += __shfl_xor(sm, 2, 64);
            sm += __shfl_xor(sm, 4, 64);
            sm += __shfl_xor(sm, 8, 64);
            float inv = 1.f / sm;
            acc[0][q] = e0 * inv; acc[1][q] = e1 * inv;
            acc[2][q] = e2 * inv; acc[3][q] = e3 * inv;
            acc[4][q] = e4 * inv; acc[5][q] = e5 * inv;
            acc[6][q] = e6 * inv; acc[7][q] = e7 * inv;
            acc[8][q] = e8 * inv;
        }
    } else {
        const float addc = (head == 1) ? 1.1f : 1.0f;
        #pragma unroll
        for (int f = 0; f < 9; ++f)
            #pragma unroll
            for (int q = 0; q < 4; ++q) acc[f][q] = eluf(acc[f][q]) + addc;
    }

    // ---- phase 3: overlay LDS with [64][140] f32 output tile ----
    __syncthreads();                      // all waves done reading the panel
    float* ot = (float*)Bs;
    {
        const int rbase = (w * 16 + g * 4) * 140 + c;
        #pragma unroll
        for (int f = 0; f < 9; ++f) {
            if (f < 8 || v8) {
                #pragma unroll
                for (int q = 0; q < 4; ++q)
                    ot[rbase + q * 140 + f * 16] = acc[f][q];
            }
        }
    }
    __syncthreads();

    // ---- phase 4: linear dwordx4 stores (2240 chunks, 64B-aligned range) ----
    float* dsth = (head == 0) ? out_pi : (head == 1) ? out_sig : out_mu;
    float* dst = dsth + (size_t)m0 * 140;
    #pragma unroll
    for (int i = 0; i < 9; ++i) {
        int idx = tid + 256 * i;
        if (idx < 2240)
            *(f32x4*)(dst + idx * 4) = *(const f32x4*)(ot + idx * 4);
    }
}

// ---------------------------------------------------------------------------
extern "C" void kernel_launch(void* const* d_in, const int* in_sizes, int n_in,
                              void* d_out, int out_size, void* d_ws, size_t ws_size,
                              hipStream_t stream) {
    const float* h_l      = (const float*)d_in[0];
    const float* h_p      = (const float*)d_in[1];
    const float* lig_pos  = (const float*)d_in[2];
    const float* prot_pos = (const float*)d_in[3];
    const int*   esrc     = (const int*)d_in[4];
    const int*   edst     = (const int*)d_in[5];
    const float* W1    = (const float*)d_in[12];
    const float* b1    = (const float*)d_in[13];
    const float* gamma = (const float*)d_in[14];
    const float* beta  = (const float*)d_in[15];
    const float* rmean = (const float*)d_in[16];
    const float* rvar  = (const float*)d_in[17];
    const float* Wpi   = (const float*)d_in[18];
    const float* bpi   = (const float*)d_in[19];
    const float* Wsig  = (const float*)d_in[20];
    const float* bsig  = (const float*)d_in[21];
    const float* Wmu   = (const float*)d_in[22];
    const float* bmu   = (const float*)d_in[23];
    const float* Wat   = (const float*)d_in[24];
    const float* bat   = (const float*)d_in[25];
    const float* Wbt   = (const float*)d_in[26];
    const float* bbt   = (const float*)d_in[27];

    char* ws = (char*)d_ws;
    unsigned short* W1T = (unsigned short*)(ws + 0);
    unsigned char*  W2q = (unsigned char*)(ws + 131072);
    float*          b2s = (float*)(ws + 241664);
    float*          a1v = (float*)(ws + 243392);
    float*          csv = (float*)(ws + 244416);
    unsigned short* Lq  = (unsigned short*)(ws + 245440);
    unsigned short* Pq  = (unsigned short*)(ws + 638656);

    float* out = (float*)d_out;
    const size_t M = M_TOT;
    float* out_pi   = out;
    float* out_sig  = out + M * 140;
    float* out_mu   = out + 2 * M * 140;
    float* out_dist = out + 3 * M * 140;
    float* out_at   = out + 3 * M * 140 + M * 14;
    float* out_bt   = out_at + 768 * 17;
    float* out_pb   = out_bt + 2048 * 5;

    hipLaunchKernelGGL(setup_kernel, dim3(432 + M_TOT / 256), dim3(256), 0, stream,
                       W1, b1, gamma, beta, rmean, rvar,
                       Wpi, bpi, Wsig, bsig, Wmu, bmu,
                       h_l, esrc, edst, Wat, bat, Wbt, bbt,
                       lig_pos, prot_pos,
                       W1T, W2q, b2s, a1v, csv, out_at, out_bt, out_dist, out_pb);

    hipLaunchKernelGGL(node_gemm, dim3(2 * (768 + 6144) / 64), dim3(256), 0, stream,
                       h_l, h_p, W1T, a1v, csv, Lq, Pq);

    hipLaunchKernelGGL(pair_kernel, dim3(M_TOT / 64, 3), dim3(256), 0, stream,
                       Lq, Pq, W2q, b2s, out_pi, out_sig, out_mu);
}

// Round 15
// 176.396 us; speedup vs baseline: 1.3193x; 1.0819x over previous
//
#include <hip/hip_runtime.h>

// ---------------------------------------------------------------------------
// MDNV2 fused kernels for MI355X (gfx950) — round 15
//
// Base = R14 (191 us, dense LDS-staged stores). New this round:
//  * pair_kernel merges the 3 per-head blocks of a tile into ONE block that
//    loops over heads: X/Xa (the dominant VALU phase) computed ONCE instead
//    of 3x; Pq/Lq L2 reads drop 3x; stores happen 3x per block (smoother
//    HBM duty cycle). LDS/occupancy unchanged (36.9 KB, 4 blocks/CU).
//  * Next head's panel loads issued during current head's epilogue.
// fp8 e4m3 GEMM2 (weights x16), bf16 Lq/Pq as before.
// ---------------------------------------------------------------------------

typedef __attribute__((ext_vector_type(4))) float f32x4;
typedef __attribute__((ext_vector_type(4))) unsigned int u32x4;
typedef __attribute__((ext_vector_type(8))) short bf16x8;

#define M_TOT 327680
#define WSCALE 16.0f
#define WDESCALE 0.0625f

__device__ __forceinline__ unsigned short f2bf(float f) {
    union { float f; unsigned int u; } v; v.f = f;
    unsigned int r = (v.u + 0x7FFFu + ((v.u >> 16) & 1u)) >> 16;  // RNE
    return (unsigned short)r;
}

__device__ __forceinline__ float eluf(float y) {
    return fmaxf(y, 0.f) + __expf(fminf(y, 0.f)) - 1.f;
}

__device__ __forceinline__ float bfhalf_lo(unsigned int u) {
    return __uint_as_float(u << 16);
}
__device__ __forceinline__ float bfhalf_hi(unsigned int u) {
    return __uint_as_float(u & 0xFFFF0000u);
}

__device__ __forceinline__ void pair_decode(int m0, int& b, int& cl, int& cp0) {
    unsigned int P = (unsigned int)m0 / 40960u;
    unsigned int r = (unsigned int)m0 % 40960u;
    if (r < 8192u) {            // even batch: 32 lig x 256 prot
        b = 2 * (int)P; cl = 96 * (int)P + (int)(r >> 8); cp0 = 768 * (int)P + (int)(r & 255u);
    } else {                    // odd batch: 64 lig x 512 prot
        unsigned int rr = r - 8192u;
        b = 2 * (int)P + 1; cl = 96 * (int)P + 32 + (int)(rr >> 9);
        cp0 = 768 * (int)P + 256 + (int)(rr & 511u);
    }
}

// ---------------------------------------------------------------------------
// setup_kernel: blocks 0..431 = weight prep + folded tails; blocks 432..1711
// = dist + pair_b (256 pair-rows each). ws layout (bytes):
//   W1T @0      : [256 n][256 k] bf16                                131072
//   W2q @131072 : fp8 [head 3][f 9][sp 4][lane 64][h 2][j 8]         110592
//   b2s @241664 : [3][144] f32 (bias x16, pads zero)                   1728
//   a1  @243392 : [256] f32
//   cs  @244416 : [256] f32
//   Lq  @245440 : [768][256] bf16
//   Pq  @638656 : [6144][256] bf16  (3 MB -> L2-resident)
// ---------------------------------------------------------------------------
__global__ void setup_kernel(const float* __restrict__ W1, const float* __restrict__ b1,
                             const float* __restrict__ gamma, const float* __restrict__ beta,
                             const float* __restrict__ rmean, const float* __restrict__ rvar,
                             const float* __restrict__ Wpi, const float* __restrict__ bpi,
                             const float* __restrict__ Wsig, const float* __restrict__ bsig,
                             const float* __restrict__ Wmu, const float* __restrict__ bmu,
                             const float* __restrict__ h_l,
                             const int* __restrict__ esrc, const int* __restrict__ edst,
                             const float* __restrict__ Wat, const float* __restrict__ bat,
                             const float* __restrict__ Wbt, const float* __restrict__ bbt,
                             const float* __restrict__ lig_pos, const float* __restrict__ prot_pos,
                             unsigned short* __restrict__ W1T, unsigned char* __restrict__ W2q,
                             float* __restrict__ b2s, float* __restrict__ a1v, float* __restrict__ csv,
                             float* __restrict__ out_at, float* __restrict__ out_bt,
                             float* __restrict__ out_dist, float* __restrict__ out_pb) {
    if (blockIdx.x >= 432) {
        // ---- dist + pair_b: 256 pair-rows per block ----
        const int m0 = (blockIdx.x - 432) * 256;
        int b, cl, cp0;
        pair_decode(m0, b, cl, cp0);
        const int rw = threadIdx.x;
        float lx = lig_pos[cl * 3 + 0];
        float ly = lig_pos[cl * 3 + 1];
        float lz = lig_pos[cl * 3 + 2];
        const float* pp = prot_pos + (size_t)(cp0 + rw) * 42;
        float* dr = out_dist + (size_t)(m0 + rw) * 14;
        #pragma unroll
        for (int a = 0; a < 14; ++a) {
            float dx = lx - pp[a * 3 + 0];
            float dy = ly - pp[a * 3 + 1];
            float dz = lz - pp[a * 3 + 2];
            dr[a] = sqrtf(dx * dx + dy * dy + dz * dz);
        }
        out_pb[m0 + rw] = (float)b;
        return;
    }

    int idx = blockIdx.x * 256 + threadIdx.x;          // 432 blocks -> 110592
    {
        int j    = idx & 7;
        int h    = (idx >> 3) & 1;
        int lane = (idx >> 4) & 63;
        int sp   = (idx >> 10) & 3;
        int t    = idx >> 12;                          // 0..26
        int f    = t % 9;
        int head = t / 9;
        int k    = (sp * 2 + h) * 32 + (lane >> 4) * 8 + j;
        int col  = f * 16 + (lane & 15);
        float v = 0.f;
        if (col < 140) {
            const float* Wh = (head == 0) ? Wpi : (head == 1) ? Wsig : Wmu;
            v = Wh[k * 140 + col] * WSCALE;
        }
        W2q[idx] = (unsigned char)(__builtin_amdgcn_cvt_pk_fp8_f32(v, 0.f, 0, false) & 0xFF);
    }
    if (idx < 256 * 256) {                             // W1T[n][k] = W1[k][n], coalesced reads
        int n = idx & 255, k = idx >> 8;
        W1T[n * 256 + k] = f2bf(W1[k * 256 + n]);
    }
    if (idx < 432) {                                   // b2s[head][col]
        int head = idx / 144, col = idx % 144;
        float v = 0.f;
        if (col < 140) v = (head == 0) ? bpi[col] : (head == 1) ? bsig[col] : bmu[col];
        b2s[idx] = v * WSCALE;
    }
    if (idx < 256) {
        float s = gamma[idx] * rsqrtf(rvar[idx] + 1e-5f);
        a1v[idx] = s;
        csv[idx] = s * (b1[idx] - rmean[idx]) + beta[idx];
    }
    // ---- folded tail: atom_types [768,17], bond_types [2048,5] ----
    if (idx < 768 * 17) {
        int row = idx / 17, c = idx % 17;
        const float* hr = h_l + (size_t)row * 128;
        float s = bat[c];
        #pragma unroll 4
        for (int k = 0; k < 128; ++k) s += hr[k] * Wat[k * 17 + c];
        out_at[idx] = s;
    } else if (idx < 768 * 17 + 2048 * 5) {
        int t2 = idx - 768 * 17;
        int e = t2 / 5, c = t2 % 5;
        const float* hs = h_l + (size_t)esrc[e] * 128;
        const float* hd = h_l + (size_t)edst[e] * 128;
        float s = bbt[c];
        #pragma unroll 4
        for (int k = 0; k < 128; ++k)
            s += hs[k] * Wbt[k * 5 + c] + hd[k] * Wbt[(k + 128) * 5 + c];
        out_bt[t2] = s;
    }
}

// ---------------------------------------------------------------------------
// node_gemm: Lq (BN shift folded) / Pq (scale only), bf16 output.
// grid 216 = 108 row-blocks x 2 N-halves (8 fragments each).
// ---------------------------------------------------------------------------
__global__ __launch_bounds__(256, 2) void node_gemm(
        const float* __restrict__ h_l, const float* __restrict__ h_p,
        const unsigned short* __restrict__ W1T,
        const float* __restrict__ a1v, const float* __restrict__ csv,
        unsigned short* __restrict__ Lq, unsigned short* __restrict__ Pq) {
    const int tid = threadIdx.x, lane = tid & 63, w = tid >> 6;
    const int cGrp = lane & 15, g = lane >> 4;
    const int nh   = blockIdx.x & 1;
    const int row0 = (blockIdx.x >> 1) * 64;
    const bool isLig = row0 < 768;
    const float* src = isLig ? (h_l + (size_t)row0 * 128) : (h_p + (size_t)(row0 - 768) * 128);
    unsigned short* dst = isLig ? (Lq + (size_t)row0 * 256) : (Pq + (size_t)(row0 - 768) * 256);
    const int koff = isLig ? 0 : 128;

    f32x4 acc[8];
    #pragma unroll
    for (int fn = 0; fn < 8; ++fn) acc[fn] = (f32x4){0.f, 0.f, 0.f, 0.f};

    #pragma unroll
    for (int fk = 0; fk < 4; ++fk) {
        const float* ap = src + (size_t)(w * 16 + cGrp) * 128 + fk * 32 + g * 8;
        f32x4 qa = *(const f32x4*)ap;
        f32x4 qb = *(const f32x4*)(ap + 4);
        bf16x8 af;
        af[0] = (short)f2bf(qa[0]); af[1] = (short)f2bf(qa[1]);
        af[2] = (short)f2bf(qa[2]); af[3] = (short)f2bf(qa[3]);
        af[4] = (short)f2bf(qb[0]); af[5] = (short)f2bf(qb[1]);
        af[6] = (short)f2bf(qb[2]); af[7] = (short)f2bf(qb[3]);
        #pragma unroll
        for (int fn = 0; fn < 8; ++fn) {
            int n = nh * 128 + fn * 16 + cGrp;
            bf16x8 bf = *(const bf16x8*)(W1T + (size_t)n * 256 + koff + fk * 32 + g * 8);
            acc[fn] = __builtin_amdgcn_mfma_f32_16x16x32_bf16(af, bf, acc[fn], 0, 0, 0);
        }
    }
    #pragma unroll
    for (int fn = 0; fn < 8; ++fn) {
        int h = nh * 128 + fn * 16 + cGrp;
        float s = a1v[h];
        float c0 = isLig ? csv[h] : 0.f;
        #pragma unroll
        for (int rg = 0; rg < 4; ++rg)
            dst[(size_t)(w * 16 + g * 4 + rg) * 256 + h] = f2bf(s * acc[fn][rg] + c0);
    }
}

// ---------------------------------------------------------------------------
// pair_kernel: grid 5120, block 256 (4 waves). ONE block = one 64-row tile,
// loops over the 3 heads. X/Xa computed once. Per head:
//   stage panel -> barrier -> K-loop -> epilogue (+ issue next panel loads)
//   -> barrier -> overlay [64][140] output tile -> barrier -> linear stores
//   -> barrier (before next panel write).
// ---------------------------------------------------------------------------
__global__ __launch_bounds__(256, 4) void pair_kernel(
        const unsigned short* __restrict__ Lq, const unsigned short* __restrict__ Pq,
        const unsigned char* __restrict__ W2q, const float* __restrict__ b2s,
        float* __restrict__ out_pi, float* __restrict__ out_sig, float* __restrict__ out_mu) {

    __shared__ __align__(16) unsigned char Bs[36864];   // panel / output tile overlay

    const int tid = threadIdx.x, lane = tid & 63, w = tid >> 6;
    const int c = lane & 15, g = lane >> 4;
    const int m0 = blockIdx.x * 64;

    int b, cl, cp0;
    pair_decode(m0, b, cl, cp0);

    // ---- issue head-0 panel loads ----
    u32x4 stg[9];
    #pragma unroll
    for (int i = 0; i < 9; ++i)
        stg[i] = *(const u32x4*)(W2q + (size_t)(tid + 256 * i) * 16);

    // ---- X = fp8(elu(Lq+Pq)) once, A-fragment layout ----
    const int row = w * 16 + c;
    const unsigned short* pqp = Pq + (size_t)(cp0 + row) * 256;
    const unsigned short* lqp = Lq + (size_t)cl * 256;
    long Xa[8];
    #pragma unroll
    for (int s = 0; s < 8; ++s) {
        u32x4 pv = *(const u32x4*)(pqp + s * 32 + g * 8);
        u32x4 lv = *(const u32x4*)(lqp + s * 32 + g * 8);
        float y0 = eluf(bfhalf_lo(pv[0]) + bfhalf_lo(lv[0]));
        float y1 = eluf(bfhalf_hi(pv[0]) + bfhalf_hi(lv[0]));
        float y2 = eluf(bfhalf_lo(pv[1]) + bfhalf_lo(lv[1]));
        float y3 = eluf(bfhalf_hi(pv[1]) + bfhalf_hi(lv[1]));
        float y4 = eluf(bfhalf_lo(pv[2]) + bfhalf_lo(lv[2]));
        float y5 = eluf(bfhalf_hi(pv[2]) + bfhalf_hi(lv[2]));
        float y6 = eluf(bfhalf_lo(pv[3]) + bfhalf_lo(lv[3]));
        float y7 = eluf(bfhalf_hi(pv[3]) + bfhalf_hi(lv[3]));
        unsigned int lo = (unsigned int)__builtin_amdgcn_cvt_pk_fp8_f32(y0, y1, 0, false);
        lo = (unsigned int)__builtin_amdgcn_cvt_pk_fp8_f32(y2, y3, (int)lo, true);
        unsigned int hi = (unsigned int)__builtin_amdgcn_cvt_pk_fp8_f32(y4, y5, 0, false);
        hi = (unsigned int)__builtin_amdgcn_cvt_pk_fp8_f32(y6, y7, (int)hi, true);
        Xa[s] = (long)(((unsigned long long)hi << 32) | (unsigned long long)lo);
    }

    const bool v8 = (c < 12);   // frag 8 covers cols 128..143, valid < 140

    #pragma unroll
    for (int head = 0; head < 3; ++head) {
        // ---- write staged panel to LDS, barrier ----
        #pragma unroll
        for (int i = 0; i < 9; ++i)
            *(u32x4*)(Bs + (size_t)(tid + 256 * i) * 16) = stg[i];
        __syncthreads();

        // ---- bias (x16 prescaled) ----
        float bb[9];
        #pragma unroll
        for (int f = 0; f < 9; ++f) bb[f] = b2s[head * 144 + f * 16 + c];

        // ---- K-loop: 36 conflict-free ds_read_b128 + 72 fp8 MFMA ----
        f32x4 acc[9];
        #pragma unroll
        for (int f = 0; f < 9; ++f) acc[f] = (f32x4){bb[f], bb[f], bb[f], bb[f]};

        #pragma unroll
        for (int sp = 0; sp < 4; ++sp) {
            long xa0 = Xa[2 * sp], xa1 = Xa[2 * sp + 1];
            #pragma unroll
            for (int f = 0; f < 9; ++f) {
                u32x4 bq = *(const u32x4*)(Bs + f * 4096 + sp * 1024 + lane * 16);
                long b0 = (long)(((unsigned long long)bq[1] << 32) | (unsigned long long)bq[0]);
                long b1 = (long)(((unsigned long long)bq[3] << 32) | (unsigned long long)bq[2]);
                acc[f] = __builtin_amdgcn_mfma_f32_16x16x32_fp8_fp8(xa0, b0, acc[f], 0, 0, 0);
                acc[f] = __builtin_amdgcn_mfma_f32_16x16x32_fp8_fp8(xa1, b1, acc[f], 0, 0, 0);
            }
        }

        // ---- issue next head's panel loads (hide L2 latency under epilogue) ----
        if (head < 2) {
            const unsigned char* wsrc = W2q + (size_t)(head + 1) * 36864;
            #pragma unroll
            for (int i = 0; i < 9; ++i)
                stg[i] = *(const u32x4*)(wsrc + (size_t)(tid + 256 * i) * 16);
        }

        // ---- epilogue math in regs ----
        #pragma unroll
        for (int f = 0; f < 9; ++f)
            #pragma unroll
            for (int q = 0; q < 4; ++q) acc[f][q] *= WDESCALE;

        if (head == 0) {
            // pi softmax, no max-subtraction (|logit| << f32 exp overflow bound)
            #pragma unroll
            for (int q = 0; q < 4; ++q) {
                float e0 = __expf(acc[0][q]), e1 = __expf(acc[1][q]);
                float e2 = __expf(acc[2][q]), e3 = __expf(acc[3][q]);
                float e4 = __expf(acc[4][q]), e5 = __expf(acc[5][q]);
                float e6 = __expf(acc[6][q]), e7 = __expf(acc[7][q]);
                float e8 = v8 ? __expf(acc[8][q]) : 0.f;
                float sm = ((e0 + e1) + (e2 + e3)) + ((e4 + e5) + (e6 + e7)) + e8;
                sm += __shfl_xor(sm, 1, 64);
                sm += __shfl_xor(sm, 2, 64);
                sm += __shfl_xor(sm, 4, 64);
                sm += __shfl_xor(sm, 8, 64);
                float inv = 1.f / sm;
                acc[0][q] = e0 * inv; acc[1][q] = e1 * inv;
                acc[2][q] = e2 * inv; acc[3][q] = e3 * inv;
                acc[4][q] = e4 * inv; acc[5][q] = e5 * inv;
                acc[6][q] = e6 * inv; acc[7][q] = e7 * inv;
                acc[8][q] = e8 * inv;
            }
        } else {
            const float addc = (head == 1) ? 1.1f : 1.0f;
            #pragma unroll
            for (int f = 0; f < 9; ++f)
                #pragma unroll
                for (int q = 0; q < 4; ++q) acc[f][q] = eluf(acc[f][q]) + addc;
        }

        // ---- overlay LDS with [64][140] f32 output tile ----
        __syncthreads();                  // all waves done reading the panel
        float* ot = (float*)Bs;
        {
            const int rbase = (w * 16 + g * 4) * 140 + c;
            #pragma unroll
            for (int f = 0; f < 9; ++f) {
                if (f < 8 || v8) {
                    #pragma unroll
                    for (int q = 0; q < 4; ++q)
                        ot[rbase + q * 140 + f * 16] = acc[f][q];
                }
            }
        }
        __syncthreads();

        // ---- linear dwordx4 stores (2240 chunks, 64B-aligned range) ----
        float* dsth = (head == 0) ? out_pi : (head == 1) ? out_sig : out_mu;
        float* dst = dsth + (size_t)m0 * 140;
        #pragma unroll
        for (int i = 0; i < 9; ++i) {
            int idx = tid + 256 * i;
            if (idx < 2240)
                *(f32x4*)(dst + idx * 4) = *(const f32x4*)(ot + idx * 4);
        }

        if (head < 2) __syncthreads();    // store reads done before next panel write
    }
}

// ---------------------------------------------------------------------------
extern "C" void kernel_launch(void* const* d_in, const int* in_sizes, int n_in,
                              void* d_out, int out_size, void* d_ws, size_t ws_size,
                              hipStream_t stream) {
    const float* h_l      = (const float*)d_in[0];
    const float* h_p      = (const float*)d_in[1];
    const float* lig_pos  = (const float*)d_in[2];
    const float* prot_pos = (const float*)d_in[3];
    const int*   esrc     = (const int*)d_in[4];
    const int*   edst     = (const int*)d_in[5];
    const float* W1    = (const float*)d_in[12];
    const float* b1    = (const float*)d_in[13];
    const float* gamma = (const float*)d_in[14];
    const float* beta  = (const float*)d_in[15];
    const float* rmean = (const float*)d_in[16];
    const float* rvar  = (const float*)d_in[17];
    const float* Wpi   = (const float*)d_in[18];
    const float* bpi   = (const float*)d_in[19];
    const float* Wsig  = (const float*)d_in[20];
    const float* bsig  = (const float*)d_in[21];
    const float* Wmu   = (const float*)d_in[22];
    const float* bmu   = (const float*)d_in[23];
    const float* Wat   = (const float*)d_in[24];
    const float* bat   = (const float*)d_in[25];
    const float* Wbt   = (const float*)d_in[26];
    const float* bbt   = (const float*)d_in[27];

    char* ws = (char*)d_ws;
    unsigned short* W1T = (unsigned short*)(ws + 0);
    unsigned char*  W2q = (unsigned char*)(ws + 131072);
    float*          b2s = (float*)(ws + 241664);
    float*          a1v = (float*)(ws + 243392);
    float*          csv = (float*)(ws + 244416);
    unsigned short* Lq  = (unsigned short*)(ws + 245440);
    unsigned short* Pq  = (unsigned short*)(ws + 638656);

    float* out = (float*)d_out;
    const size_t M = M_TOT;
    float* out_pi   = out;
    float* out_sig  = out + M * 140;
    float* out_mu   = out + 2 * M * 140;
    float* out_dist = out + 3 * M * 140;
    float* out_at   = out + 3 * M * 140 + M * 14;
    float* out_bt   = out_at + 768 * 17;
    float* out_pb   = out_bt + 2048 * 5;

    hipLaunchKernelGGL(setup_kernel, dim3(432 + M_TOT / 256), dim3(256), 0, stream,
                       W1, b1, gamma, beta, rmean, rvar,
                       Wpi, bpi, Wsig, bsig, Wmu, bmu,
                       h_l, esrc, edst, Wat, bat, Wbt, bbt,
                       lig_pos, prot_pos,
                       W1T, W2q, b2s, a1v, csv, out_at, out_bt, out_dist, out_pb);

    hipLaunchKernelGGL(node_gemm, dim3(2 * (768 + 6144) / 64), dim3(256), 0, stream,
                       h_l, h_p, W1T, a1v, csv, Lq, Pq);

    hipLaunchKernelGGL(pair_kernel, dim3(M_TOT / 64), dim3(256), 0, stream,
                       Lq, Pq, W2q, b2s, out_pi, out_sig, out_mu);
}

// Round 16
// 166.506 us; speedup vs baseline: 1.3977x; 1.0594x over previous
//
#include <hip/hip_runtime.h>

// ---------------------------------------------------------------------------
// MDNV2 fused kernels for MI355X (gfx950) — round 16
//
// Base = R15 (176 us). Single lever this round: LAUNCH FUSION.
//  * node_gemm folded into setup_kernel as a third block range (dispatched
//    first). Node blocks are self-contained: stage their own 128x128 W1
//    quadrant into LDS (bf16, transposed, stride-136 pad) and compute BN
//    scale/shift inline -> no dependency on prep outputs, no extra launch.
//  * prep drops dead W1T / a1v / csv sections.
//  * pair_kernel byte-identical to R15 (X once per tile, head loop,
//    dense LDS-staged stores).
// fp8 e4m3 GEMM2 (weights x16), bf16 Lq/Pq as before.
// ---------------------------------------------------------------------------

typedef __attribute__((ext_vector_type(4))) float f32x4;
typedef __attribute__((ext_vector_type(4))) unsigned int u32x4;
typedef __attribute__((ext_vector_type(8))) short bf16x8;

#define M_TOT 327680
#define WSCALE 16.0f
#define WDESCALE 0.0625f

#define NODE_BLOCKS 216
#define PREP_BLOCKS 432
#define DIST_BLOCKS 1280      // M_TOT / 256

__device__ __forceinline__ unsigned short f2bf(float f) {
    union { float f; unsigned int u; } v; v.f = f;
    unsigned int r = (v.u + 0x7FFFu + ((v.u >> 16) & 1u)) >> 16;  // RNE
    return (unsigned short)r;
}

__device__ __forceinline__ float eluf(float y) {
    return fmaxf(y, 0.f) + __expf(fminf(y, 0.f)) - 1.f;
}

__device__ __forceinline__ float bfhalf_lo(unsigned int u) {
    return __uint_as_float(u << 16);
}
__device__ __forceinline__ float bfhalf_hi(unsigned int u) {
    return __uint_as_float(u & 0xFFFF0000u);
}

__device__ __forceinline__ void pair_decode(int m0, int& b, int& cl, int& cp0) {
    unsigned int P = (unsigned int)m0 / 40960u;
    unsigned int r = (unsigned int)m0 % 40960u;
    if (r < 8192u) {            // even batch: 32 lig x 256 prot
        b = 2 * (int)P; cl = 96 * (int)P + (int)(r >> 8); cp0 = 768 * (int)P + (int)(r & 255u);
    } else {                    // odd batch: 64 lig x 512 prot
        unsigned int rr = r - 8192u;
        b = 2 * (int)P + 1; cl = 96 * (int)P + 32 + (int)(rr >> 9);
        cp0 = 768 * (int)P + 256 + (int)(rr & 511u);
    }
}

// ---------------------------------------------------------------------------
// setup_kernel: grid 1928 x 256.
//   blocks [0,216)      : node_gemm (self-contained, LDS-local W1 quadrant)
//   blocks [216,648)    : weight prep (W2q, b2s) + atom/bond tails
//   blocks [648,1928)   : dist + pair_b (256 pair-rows each)
// ws layout (bytes):
//   W2q @131072 : fp8 [head 3][f 9][sp 4][lane 64][h 2][j 8]         110592
//   b2s @241664 : [3][144] f32 (bias x16, pads zero)                   1728
//   Lq  @245440 : [768][256] bf16
//   Pq  @638656 : [6144][256] bf16  (3 MB -> L2-resident)
// ---------------------------------------------------------------------------
__global__ void setup_kernel(const float* __restrict__ W1, const float* __restrict__ b1,
                             const float* __restrict__ gamma, const float* __restrict__ beta,
                             const float* __restrict__ rmean, const float* __restrict__ rvar,
                             const float* __restrict__ Wpi, const float* __restrict__ bpi,
                             const float* __restrict__ Wsig, const float* __restrict__ bsig,
                             const float* __restrict__ Wmu, const float* __restrict__ bmu,
                             const float* __restrict__ h_l, const float* __restrict__ h_p,
                             const int* __restrict__ esrc, const int* __restrict__ edst,
                             const float* __restrict__ Wat, const float* __restrict__ bat,
                             const float* __restrict__ Wbt, const float* __restrict__ bbt,
                             const float* __restrict__ lig_pos, const float* __restrict__ prot_pos,
                             unsigned char* __restrict__ W2q, float* __restrict__ b2s,
                             unsigned short* __restrict__ Lq, unsigned short* __restrict__ Pq,
                             float* __restrict__ out_at, float* __restrict__ out_bt,
                             float* __restrict__ out_dist, float* __restrict__ out_pb) {

    __shared__ __align__(16) unsigned short Wl[128 * 136];   // 34816 B (node blocks)

    const int bid = blockIdx.x;
    const int tid = threadIdx.x;

    if (bid < NODE_BLOCKS) {
        // ================= node_gemm =================
        const int nh   = bid & 1;
        const int row0 = (bid >> 1) * 64;
        const bool isLig = row0 < 768;
        const float* src = isLig ? (h_l + (size_t)row0 * 128) : (h_p + (size_t)(row0 - 768) * 128);
        unsigned short* dst = isLig ? (Lq + (size_t)row0 * 256) : (Pq + (size_t)(row0 - 768) * 256);
        const int koff = isLig ? 0 : 128;

        // ---- stage W1 quadrant [koff..koff+128) x [nh*128..+128) -> LDS
        //      Wl[nn][kk] = bf16(W1[koff+kk][nh*128+nn]), stride 136 ----
        {
            const int nn = tid & 127;
            const int kb = tid >> 7;              // 0 or 1
            #pragma unroll 8
            for (int i = 0; i < 64; ++i) {
                int kk = i * 2 + kb;
                Wl[nn * 136 + kk] = f2bf(W1[(size_t)(koff + kk) * 256 + nh * 128 + nn]);
            }
        }
        __syncthreads();

        const int lane = tid & 63, w = tid >> 6;
        const int cGrp = lane & 15, g = lane >> 4;

        f32x4 acc[8];
        #pragma unroll
        for (int fn = 0; fn < 8; ++fn) acc[fn] = (f32x4){0.f, 0.f, 0.f, 0.f};

        #pragma unroll
        for (int fk = 0; fk < 4; ++fk) {
            const float* ap = src + (size_t)(w * 16 + cGrp) * 128 + fk * 32 + g * 8;
            f32x4 qa = *(const f32x4*)ap;
            f32x4 qb = *(const f32x4*)(ap + 4);
            bf16x8 af;
            af[0] = (short)f2bf(qa[0]); af[1] = (short)f2bf(qa[1]);
            af[2] = (short)f2bf(qa[2]); af[3] = (short)f2bf(qa[3]);
            af[4] = (short)f2bf(qb[0]); af[5] = (short)f2bf(qb[1]);
            af[6] = (short)f2bf(qb[2]); af[7] = (short)f2bf(qb[3]);
            #pragma unroll
            for (int fn = 0; fn < 8; ++fn) {
                bf16x8 bf = *(const bf16x8*)(Wl + (fn * 16 + cGrp) * 136 + fk * 32 + g * 8);
                acc[fn] = __builtin_amdgcn_mfma_f32_16x16x32_bf16(af, bf, acc[fn], 0, 0, 0);
            }
        }
        #pragma unroll
        for (int fn = 0; fn < 8; ++fn) {
            int h = nh * 128 + fn * 16 + cGrp;
            float s  = gamma[h] * rsqrtf(rvar[h] + 1e-5f);
            float c0 = isLig ? (s * (b1[h] - rmean[h]) + beta[h]) : 0.f;
            #pragma unroll
            for (int rg = 0; rg < 4; ++rg)
                dst[(size_t)(w * 16 + g * 4 + rg) * 256 + h] = f2bf(s * acc[fn][rg] + c0);
        }
        return;
    }

    if (bid >= NODE_BLOCKS + PREP_BLOCKS) {
        // ================= dist + pair_b =================
        const int m0 = (bid - NODE_BLOCKS - PREP_BLOCKS) * 256;
        int b, cl, cp0;
        pair_decode(m0, b, cl, cp0);
        const int rw = tid;
        float lx = lig_pos[cl * 3 + 0];
        float ly = lig_pos[cl * 3 + 1];
        float lz = lig_pos[cl * 3 + 2];
        const float* pp = prot_pos + (size_t)(cp0 + rw) * 42;
        float* dr = out_dist + (size_t)(m0 + rw) * 14;
        #pragma unroll
        for (int a = 0; a < 14; ++a) {
            float dx = lx - pp[a * 3 + 0];
            float dy = ly - pp[a * 3 + 1];
            float dz = lz - pp[a * 3 + 2];
            dr[a] = sqrtf(dx * dx + dy * dy + dz * dz);
        }
        out_pb[m0 + rw] = (float)b;
        return;
    }

    // ================= weight prep + tails =================
    int idx = (bid - NODE_BLOCKS) * 256 + tid;         // 432 blocks -> 110592
    {
        int j    = idx & 7;
        int h    = (idx >> 3) & 1;
        int lane = (idx >> 4) & 63;
        int sp   = (idx >> 10) & 3;
        int t    = idx >> 12;                          // 0..26
        int f    = t % 9;
        int head = t / 9;
        int k    = (sp * 2 + h) * 32 + (lane >> 4) * 8 + j;
        int col  = f * 16 + (lane & 15);
        float v = 0.f;
        if (col < 140) {
            const float* Wh = (head == 0) ? Wpi : (head == 1) ? Wsig : Wmu;
            v = Wh[k * 140 + col] * WSCALE;
        }
        W2q[idx] = (unsigned char)(__builtin_amdgcn_cvt_pk_fp8_f32(v, 0.f, 0, false) & 0xFF);
    }
    if (idx < 432) {                                   // b2s[head][col]
        int head = idx / 144, col = idx % 144;
        float v = 0.f;
        if (col < 140) v = (head == 0) ? bpi[col] : (head == 1) ? bsig[col] : bmu[col];
        b2s[idx] = v * WSCALE;
    }
    // ---- folded tail: atom_types [768,17], bond_types [2048,5] ----
    if (idx < 768 * 17) {
        int row = idx / 17, c = idx % 17;
        const float* hr = h_l + (size_t)row * 128;
        float s = bat[c];
        #pragma unroll 4
        for (int k = 0; k < 128; ++k) s += hr[k] * Wat[k * 17 + c];
        out_at[idx] = s;
    } else if (idx < 768 * 17 + 2048 * 5) {
        int t2 = idx - 768 * 17;
        int e = t2 / 5, c = t2 % 5;
        const float* hs = h_l + (size_t)esrc[e] * 128;
        const float* hd = h_l + (size_t)edst[e] * 128;
        float s = bbt[c];
        #pragma unroll 4
        for (int k = 0; k < 128; ++k)
            s += hs[k] * Wbt[k * 5 + c] + hd[k] * Wbt[(k + 128) * 5 + c];
        out_bt[t2] = s;
    }
}

// ---------------------------------------------------------------------------
// pair_kernel: grid 5120, block 256 (4 waves). ONE block = one 64-row tile,
// loops over the 3 heads. X/Xa computed once. Per head:
//   stage panel -> barrier -> K-loop -> epilogue (+ issue next panel loads)
//   -> barrier -> overlay [64][140] output tile -> barrier -> linear stores
//   -> barrier (before next panel write).          (byte-identical to R15)
// ---------------------------------------------------------------------------
__global__ __launch_bounds__(256, 4) void pair_kernel(
        const unsigned short* __restrict__ Lq, const unsigned short* __restrict__ Pq,
        const unsigned char* __restrict__ W2q, const float* __restrict__ b2s,
        float* __restrict__ out_pi, float* __restrict__ out_sig, float* __restrict__ out_mu) {

    __shared__ __align__(16) unsigned char Bs[36864];   // panel / output tile overlay

    const int tid = threadIdx.x, lane = tid & 63, w = tid >> 6;
    const int c = lane & 15, g = lane >> 4;
    const int m0 = blockIdx.x * 64;

    int b, cl, cp0;
    pair_decode(m0, b, cl, cp0);

    // ---- issue head-0 panel loads ----
    u32x4 stg[9];
    #pragma unroll
    for (int i = 0; i < 9; ++i)
        stg[i] = *(const u32x4*)(W2q + (size_t)(tid + 256 * i) * 16);

    // ---- X = fp8(elu(Lq+Pq)) once, A-fragment layout ----
    const int row = w * 16 + c;
    const unsigned short* pqp = Pq + (size_t)(cp0 + row) * 256;
    const unsigned short* lqp = Lq + (size_t)cl * 256;
    long Xa[8];
    #pragma unroll
    for (int s = 0; s < 8; ++s) {
        u32x4 pv = *(const u32x4*)(pqp + s * 32 + g * 8);
        u32x4 lv = *(const u32x4*)(lqp + s * 32 + g * 8);
        float y0 = eluf(bfhalf_lo(pv[0]) + bfhalf_lo(lv[0]));
        float y1 = eluf(bfhalf_hi(pv[0]) + bfhalf_hi(lv[0]));
        float y2 = eluf(bfhalf_lo(pv[1]) + bfhalf_lo(lv[1]));
        float y3 = eluf(bfhalf_hi(pv[1]) + bfhalf_hi(lv[1]));
        float y4 = eluf(bfhalf_lo(pv[2]) + bfhalf_lo(lv[2]));
        float y5 = eluf(bfhalf_hi(pv[2]) + bfhalf_hi(lv[2]));
        float y6 = eluf(bfhalf_lo(pv[3]) + bfhalf_lo(lv[3]));
        float y7 = eluf(bfhalf_hi(pv[3]) + bfhalf_hi(lv[3]));
        unsigned int lo = (unsigned int)__builtin_amdgcn_cvt_pk_fp8_f32(y0, y1, 0, false);
        lo = (unsigned int)__builtin_amdgcn_cvt_pk_fp8_f32(y2, y3, (int)lo, true);
        unsigned int hi = (unsigned int)__builtin_amdgcn_cvt_pk_fp8_f32(y4, y5, 0, false);
        hi = (unsigned int)__builtin_amdgcn_cvt_pk_fp8_f32(y6, y7, (int)hi, true);
        Xa[s] = (long)(((unsigned long long)hi << 32) | (unsigned long long)lo);
    }

    const bool v8 = (c < 12);   // frag 8 covers cols 128..143, valid < 140

    #pragma unroll
    for (int head = 0; head < 3; ++head) {
        // ---- write staged panel to LDS, barrier ----
        #pragma unroll
        for (int i = 0; i < 9; ++i)
            *(u32x4*)(Bs + (size_t)(tid + 256 * i) * 16) = stg[i];
        __syncthreads();

        // ---- bias (x16 prescaled) ----
        float bb[9];
        #pragma unroll
        for (int f = 0; f < 9; ++f) bb[f] = b2s[head * 144 + f * 16 + c];

        // ---- K-loop: 36 conflict-free ds_read_b128 + 72 fp8 MFMA ----
        f32x4 acc[9];
        #pragma unroll
        for (int f = 0; f < 9; ++f) acc[f] = (f32x4){bb[f], bb[f], bb[f], bb[f]};

        #pragma unroll
        for (int sp = 0; sp < 4; ++sp) {
            long xa0 = Xa[2 * sp], xa1 = Xa[2 * sp + 1];
            #pragma unroll
            for (int f = 0; f < 9; ++f) {
                u32x4 bq = *(const u32x4*)(Bs + f * 4096 + sp * 1024 + lane * 16);
                long b0 = (long)(((unsigned long long)bq[1] << 32) | (unsigned long long)bq[0]);
                long b1 = (long)(((unsigned long long)bq[3] << 32) | (unsigned long long)bq[2]);
                acc[f] = __builtin_amdgcn_mfma_f32_16x16x32_fp8_fp8(xa0, b0, acc[f], 0, 0, 0);
                acc[f] = __builtin_amdgcn_mfma_f32_16x16x32_fp8_fp8(xa1, b1, acc[f], 0, 0, 0);
            }
        }

        // ---- issue next head's panel loads (hide L2 latency under epilogue) ----
        if (head < 2) {
            const unsigned char* wsrc = W2q + (size_t)(head + 1) * 36864;
            #pragma unroll
            for (int i = 0; i < 9; ++i)
                stg[i] = *(const u32x4*)(wsrc + (size_t)(tid + 256 * i) * 16);
        }

        // ---- epilogue math in regs ----
        #pragma unroll
        for (int f = 0; f < 9; ++f)
            #pragma unroll
            for (int q = 0; q < 4; ++q) acc[f][q] *= WDESCALE;

        if (head == 0) {
            // pi softmax, no max-subtraction (|logit| << f32 exp overflow bound)
            #pragma unroll
            for (int q = 0; q < 4; ++q) {
                float e0 = __expf(acc[0][q]), e1 = __expf(acc[1][q]);
                float e2 = __expf(acc[2][q]), e3 = __expf(acc[3][q]);
                float e4 = __expf(acc[4][q]), e5 = __expf(acc[5][q]);
                float e6 = __expf(acc[6][q]), e7 = __expf(acc[7][q]);
                float e8 = v8 ? __expf(acc[8][q]) : 0.f;
                float sm = ((e0 + e1) + (e2 + e3)) + ((e4 + e5) + (e6 + e7)) + e8;
                sm += __shfl_xor(sm, 1, 64);
                sm += __shfl_xor(sm, 2, 64);
                sm += __shfl_xor(sm, 4, 64);
                sm += __shfl_xor(sm, 8, 64);
                float inv = 1.f / sm;
                acc[0][q] = e0 * inv; acc[1][q] = e1 * inv;
                acc[2][q] = e2 * inv; acc[3][q] = e3 * inv;
                acc[4][q] = e4 * inv; acc[5][q] = e5 * inv;
                acc[6][q] = e6 * inv; acc[7][q] = e7 * inv;
                acc[8][q] = e8 * inv;
            }
        } else {
            const float addc = (head == 1) ? 1.1f : 1.0f;
            #pragma unroll
            for (int f = 0; f < 9; ++f)
                #pragma unroll
                for (int q = 0; q < 4; ++q) acc[f][q] = eluf(acc[f][q]) + addc;
        }

        // ---- overlay LDS with [64][140] f32 output tile ----
        __syncthreads();                  // all waves done reading the panel
        float* ot = (float*)Bs;
        {
            const int rbase = (w * 16 + g * 4) * 140 + c;
            #pragma unroll
            for (int f = 0; f < 9; ++f) {
                if (f < 8 || v8) {
                    #pragma unroll
                    for (int q = 0; q < 4; ++q)
                        ot[rbase + q * 140 + f * 16] = acc[f][q];
                }
            }
        }
        __syncthreads();

        // ---- linear dwordx4 stores (2240 chunks, 64B-aligned range) ----
        float* dsth = (head == 0) ? out_pi : (head == 1) ? out_sig : out_mu;
        float* dst = dsth + (size_t)m0 * 140;
        #pragma unroll
        for (int i = 0; i < 9; ++i) {
            int idx = tid + 256 * i;
            if (idx < 2240)
                *(f32x4*)(dst + idx * 4) = *(const f32x4*)(ot + idx * 4);
        }

        if (head < 2) __syncthreads();    // store reads done before next panel write
    }
}

// ---------------------------------------------------------------------------
extern "C" void kernel_launch(void* const* d_in, const int* in_sizes, int n_in,
                              void* d_out, int out_size, void* d_ws, size_t ws_size,
                              hipStream_t stream) {
    const float* h_l      = (const float*)d_in[0];
    const float* h_p      = (const float*)d_in[1];
    const float* lig_pos  = (const float*)d_in[2];
    const float* prot_pos = (const float*)d_in[3];
    const int*   esrc     = (const int*)d_in[4];
    const int*   edst     = (const int*)d_in[5];
    const float* W1    = (const float*)d_in[12];
    const float* b1    = (const float*)d_in[13];
    const float* gamma = (const float*)d_in[14];
    const float* beta  = (const float*)d_in[15];
    const float* rmean = (const float*)d_in[16];
    const float* rvar  = (const float*)d_in[17];
    const float* Wpi   = (const float*)d_in[18];
    const float* bpi   = (const float*)d_in[19];
    const float* Wsig  = (const float*)d_in[20];
    const float* bsig  = (const float*)d_in[21];
    const float* Wmu   = (const float*)d_in[22];
    const float* bmu   = (const float*)d_in[23];
    const float* Wat   = (const float*)d_in[24];
    const float* bat   = (const float*)d_in[25];
    const float* Wbt   = (const float*)d_in[26];
    const float* bbt   = (const float*)d_in[27];

    char* ws = (char*)d_ws;
    unsigned char*  W2q = (unsigned char*)(ws + 131072);
    float*          b2s = (float*)(ws + 241664);
    unsigned short* Lq  = (unsigned short*)(ws + 245440);
    unsigned short* Pq  = (unsigned short*)(ws + 638656);

    float* out = (float*)d_out;
    const size_t M = M_TOT;
    float* out_pi   = out;
    float* out_sig  = out + M * 140;
    float* out_mu   = out + 2 * M * 140;
    float* out_dist = out + 3 * M * 140;
    float* out_at   = out + 3 * M * 140 + M * 14;
    float* out_bt   = out_at + 768 * 17;
    float* out_pb   = out_bt + 2048 * 5;

    hipLaunchKernelGGL(setup_kernel, dim3(NODE_BLOCKS + PREP_BLOCKS + DIST_BLOCKS), dim3(256), 0, stream,
                       W1, b1, gamma, beta, rmean, rvar,
                       Wpi, bpi, Wsig, bsig, Wmu, bmu,
                       h_l, h_p, esrc, edst, Wat, bat, Wbt, bbt,
                       lig_pos, prot_pos,
                       W2q, b2s, Lq, Pq, out_at, out_bt, out_dist, out_pb);

    hipLaunchKernelGGL(pair_kernel, dim3(M_TOT / 64), dim3(256), 0, stream,
                       Lq, Pq, W2q, b2s, out_pi, out_sig, out_mu);
}